// Round 1
// baseline (143.494 us; speedup 1.0000x reference)
//
#include <hip/hip_runtime.h>
#include <math.h>

#define LQ 2048
#define EQ 1024
#define HQ 1024
#define DQ 512
#define VQ 32000
#define MVQ 32768

// d_out layout (floats): [out1: 32768][h_new: 1024][attn_w: 2048][prob_c: 2048]
#define OUT1_OFF 0
#define HNEW_OFF 32768
#define AW_OFF   33792
#define PC_OFF   35840

// ---------------- helpers ----------------
__device__ inline float wred(float v) {
    v += __shfl_down(v, 32);
    v += __shfl_down(v, 16);
    v += __shfl_down(v, 8);
    v += __shfl_down(v, 4);
    v += __shfl_down(v, 2);
    v += __shfl_down(v, 1);
    return v;
}
__device__ inline float wred_max(float v) {
    v = fmaxf(v, __shfl_down(v, 32));
    v = fmaxf(v, __shfl_down(v, 16));
    v = fmaxf(v, __shfl_down(v, 8));
    v = fmaxf(v, __shfl_down(v, 4));
    v = fmaxf(v, __shfl_down(v, 2));
    v = fmaxf(v, __shfl_down(v, 1));
    return v;
}
__device__ inline float sigmoidf_(float x) { return 1.0f / (1.0f + expf(-x)); }

// ---------------- k_prep ----------------
// One block, 256 threads. Computes: match list -> sel_reading (exact int32
// semantics), embedded row, xcat=[embedded,h], ccat=[embedded, 0(attn_applied acc)]
__global__ __launch_bounds__(256) void k_prep(
    const int* __restrict__ inp, const float* __restrict__ hidden,
    const float* __restrict__ enc, const int* __restrict__ input_seq,
    const int* __restrict__ pre_prob, const float* __restrict__ emb,
    float* __restrict__ xcat, float* __restrict__ ccat, float* __restrict__ x2)
{
    __shared__ int s_cnt;
    __shared__ int s_list[LQ];
    int tid = threadIdx.x;
    if (tid == 0) s_cnt = 0;
    __syncthreads();
    int tok = inp[0];
    for (int l = tid; l < LQ; l += 256) {
        if (input_seq[l] == tok && pre_prob[l] != 0) {
            int p = atomicAdd(&s_cnt, 1);
            s_list[p] = l;
        }
    }
    __syncthreads();
    int nm = s_cnt;
    for (int e = tid; e < EQ; e += 256) {
        int acc = 0;
        for (int j = 0; j < nm; ++j) {
            int l = s_list[j];
            acc += (int)enc[(size_t)l * EQ + e];  // trunc-toward-zero == astype(int32)
        }
        x2[HQ + e] = (float)acc;  // sel_reading into x2[1024:2048]
    }
    int ei = (tok >= VQ) ? 2 : tok;
    for (int d = tid; d < DQ; d += 256) {
        float v = emb[(size_t)ei * DQ + d];
        xcat[d] = v;
        ccat[d] = v;
    }
    for (int i = tid; i < HQ; i += 256) {
        xcat[DQ + i] = hidden[i];
        ccat[DQ + i] = 0.0f;  // zero accumulator for attn_applied atomics
    }
}

// ---------------- k_gemm_tanh ----------------
// T[l][h] = tanhf(dot(enc[l,:], Wc[h,:]) + Wc_b[h]).  NT fp32 GEMM,
// M=2048 N=1024 K=1024, 64x64 tile, BK=32, 256 threads, 4x4 microtile.
#define BM 64
#define BN 64
#define BK 32
__global__ __launch_bounds__(256) void k_gemm_tanh(
    const float* __restrict__ A, const float* __restrict__ B,
    const float* __restrict__ bias, float* __restrict__ T)
{
    __shared__ float As[BK][BM + 4];
    __shared__ float Bs[BK][BN + 4];
    int m0 = blockIdx.y * BM;
    int n0 = blockIdx.x * BN;
    int tid = threadIdx.x;
    int tx = tid & 15, ty = tid >> 4;
    float acc[4][4] = {};
    for (int k0 = 0; k0 < EQ; k0 += BK) {
        // stage A(64x32) and B(64x32), transposed to [k][m]
        #pragma unroll
        for (int i = 0; i < 2; ++i) {
            int ff = tid + i * 256;
            int row = ff >> 3;
            int c4 = ff & 7;
            float4 a = *(const float4*)(A + (size_t)(m0 + row) * EQ + k0 + c4 * 4);
            As[c4 * 4 + 0][row] = a.x; As[c4 * 4 + 1][row] = a.y;
            As[c4 * 4 + 2][row] = a.z; As[c4 * 4 + 3][row] = a.w;
            float4 b = *(const float4*)(B + (size_t)(n0 + row) * EQ + k0 + c4 * 4);
            Bs[c4 * 4 + 0][row] = b.x; Bs[c4 * 4 + 1][row] = b.y;
            Bs[c4 * 4 + 2][row] = b.z; Bs[c4 * 4 + 3][row] = b.w;
        }
        __syncthreads();
        #pragma unroll
        for (int kk = 0; kk < BK; ++kk) {
            float4 av = *(const float4*)&As[kk][ty * 4];
            float4 bv = *(const float4*)&Bs[kk][tx * 4];
            float a[4] = {av.x, av.y, av.z, av.w};
            float b[4] = {bv.x, bv.y, bv.z, bv.w};
            #pragma unroll
            for (int i = 0; i < 4; ++i)
                #pragma unroll
                for (int j = 0; j < 4; ++j)
                    acc[i][j] = fmaf(a[i], b[j], acc[i][j]);
        }
        __syncthreads();
    }
    #pragma unroll
    for (int i = 0; i < 4; ++i) {
        int m = m0 + ty * 4 + i;
        float4 o;
        o.x = tanhf(acc[i][0] + bias[n0 + tx * 4 + 0]);
        o.y = tanhf(acc[i][1] + bias[n0 + tx * 4 + 1]);
        o.z = tanhf(acc[i][2] + bias[n0 + tx * 4 + 2]);
        o.w = tanhf(acc[i][3] + bias[n0 + tx * 4 + 3]);
        *(float4*)(T + (size_t)m * HQ + n0 + tx * 4) = o;
    }
}

// ---------------- k_attn (logits) ----------------
// logits[r] = attn_W[r,:1536] . xcat + attn_b[r].  Wave per row.
__global__ __launch_bounds__(256) void k_attn(
    const float* __restrict__ W, const float* __restrict__ b,
    const float* __restrict__ xcat, float* __restrict__ logits)
{
    int warp = threadIdx.x >> 6, lane = threadIdx.x & 63;
    int r = blockIdx.x * 4 + warp;
    const float4* Wr = (const float4*)(W + (size_t)r * 1536);
    const float4* xv = (const float4*)xcat;
    float acc = 0.0f;
    #pragma unroll
    for (int i = 0; i < 6; ++i) {
        int idx = lane + i * 64;  // 384 float4
        float4 w = Wr[idx], x = xv[idx];
        acc += w.x * x.x + w.y * x.y + w.z * x.z + w.w * x.w;
    }
    acc = wred(acc);
    if (lane == 0) logits[r] = acc + b[r];
}

// ---------------- k_softmax_L ----------------
// softmax over 2048 attn logits -> d_out[AW_OFF..]
__global__ __launch_bounds__(1024) void k_softmax_L(
    const float* __restrict__ logits, float* __restrict__ out)
{
    __shared__ float sred[16];
    int tid = threadIdx.x;
    int wid = tid >> 6, lane = tid & 63;
    float m = -3.4e38f;
    for (int i = tid; i < LQ; i += 1024) m = fmaxf(m, logits[i]);
    m = wred_max(m);
    if (lane == 0) sred[wid] = m;
    __syncthreads();
    if (tid == 0) {
        float mm = sred[0];
        for (int i = 1; i < 16; ++i) mm = fmaxf(mm, sred[i]);
        sred[0] = mm;
    }
    __syncthreads();
    m = sred[0];
    __syncthreads();
    float s = 0.0f;
    for (int i = tid; i < LQ; i += 1024) s += expf(logits[i] - m);
    s = wred(s);
    if (lane == 0) sred[wid] = s;
    __syncthreads();
    if (tid == 0) {
        float ss = 0.0f;
        for (int i = 0; i < 16; ++i) ss += sred[i];
        sred[0] = ss;
    }
    __syncthreads();
    s = sred[0];
    for (int i = tid; i < LQ; i += 1024) out[i] = expf(logits[i] - m) / s;
}

// ---------------- k_attn_applied ----------------
// ccat[DQ+e] += sum_l w[l]*enc[l][e], split over 16 l-chunks with atomics.
__global__ __launch_bounds__(256) void k_attn_applied(
    const float* __restrict__ enc, const float* __restrict__ w,
    float* __restrict__ ccat)
{
    int e = blockIdx.x * 256 + threadIdx.x;
    int l0 = blockIdx.y * 128;
    float acc = 0.0f;
    for (int l = l0; l < l0 + 128; ++l)
        acc = fmaf(w[l], enc[(size_t)l * EQ + e], acc);
    atomicAdd(&ccat[DQ + e], acc);
}

// ---------------- k_comb ----------------
// x2[r] = relu(comb_W[r,:1536] . ccat + comb_b[r])
__global__ __launch_bounds__(256) void k_comb(
    const float* __restrict__ W, const float* __restrict__ b,
    const float* __restrict__ ccat, float* __restrict__ x2)
{
    int warp = threadIdx.x >> 6, lane = threadIdx.x & 63;
    int r = blockIdx.x * 4 + warp;
    const float4* Wr = (const float4*)(W + (size_t)r * 1536);
    const float4* xv = (const float4*)ccat;
    float acc = 0.0f;
    #pragma unroll
    for (int i = 0; i < 6; ++i) {
        int idx = lane + i * 64;
        float4 w = Wr[idx], x = xv[idx];
        acc += w.x * x.x + w.y * x.y + w.z * x.z + w.w * x.w;
    }
    acc = wred(acc);
    if (lane == 0) x2[r] = fmaxf(acc + b[r], 0.0f);
}

// ---------------- k_gru_mv ----------------
// gi[r] = W_ih[r,:2048].x2 + b_ih[r]; gh[r] = W_hh[r,:1024].h + b_hh[r]
__global__ __launch_bounds__(256) void k_gru_mv(
    const float* __restrict__ W_ih, const float* __restrict__ W_hh,
    const float* __restrict__ b_ih, const float* __restrict__ b_hh,
    const float* __restrict__ x2, const float* __restrict__ h,
    float* __restrict__ gi, float* __restrict__ gh)
{
    int warp = threadIdx.x >> 6, lane = threadIdx.x & 63;
    int r = blockIdx.x * 4 + warp;
    const float4* Wi = (const float4*)(W_ih + (size_t)r * 2048);
    const float4* Wh = (const float4*)(W_hh + (size_t)r * 1024);
    const float4* xv = (const float4*)x2;
    const float4* hv = (const float4*)h;
    float a1 = 0.0f, a2 = 0.0f;
    #pragma unroll
    for (int i = 0; i < 8; ++i) {
        int idx = lane + i * 64;  // 512 float4
        float4 w = Wi[idx], x = xv[idx];
        a1 += w.x * x.x + w.y * x.y + w.z * x.z + w.w * x.w;
    }
    #pragma unroll
    for (int i = 0; i < 4; ++i) {
        int idx = lane + i * 64;  // 256 float4
        float4 w = Wh[idx], x = hv[idx];
        a2 += w.x * x.x + w.y * x.y + w.z * x.z + w.w * x.w;
    }
    a1 = wred(a1);
    a2 = wred(a2);
    if (lane == 0) {
        gi[r] = a1 + b_ih[r];
        gh[r] = a2 + b_hh[r];
    }
}

// ---------------- k_gates ----------------
__global__ __launch_bounds__(256) void k_gates(
    const float* __restrict__ gi, const float* __restrict__ gh,
    const float* __restrict__ h, float* __restrict__ hnew,
    float* __restrict__ out_h)
{
    int i = blockIdx.x * 256 + threadIdx.x;
    float r = sigmoidf_(gi[i] + gh[i]);
    float z = sigmoidf_(gi[HQ + i] + gh[HQ + i]);
    float n = tanhf(gi[2 * HQ + i] + r * gh[2 * HQ + i]);
    float hn = (1.0f - z) * n + z * h[i];
    hnew[i] = hn;
    out_h[i] = hn;
}

// ---------------- k_score_g ----------------
// score[r] = Wo_W[r,:1024].hnew + Wo_b[r], r<32000
__global__ __launch_bounds__(256) void k_score_g(
    const float* __restrict__ W, const float* __restrict__ b,
    const float* __restrict__ hnew, float* __restrict__ score)
{
    int warp = threadIdx.x >> 6, lane = threadIdx.x & 63;
    int r = blockIdx.x * 4 + warp;
    const float4* Wr = (const float4*)(W + (size_t)r * 1024);
    const float4* hv = (const float4*)hnew;
    float acc = 0.0f;
    #pragma unroll
    for (int i = 0; i < 4; ++i) {
        int idx = lane + i * 64;
        float4 w = Wr[idx], x = hv[idx];
        acc += w.x * x.x + w.y * x.y + w.z * x.z + w.w * x.w;
    }
    acc = wred(acc);
    if (lane == 0) score[r] = acc + b[r];
}

// ---------------- k_score_c ----------------
// score[VQ+l] = T[l,:1024].hnew
__global__ __launch_bounds__(256) void k_score_c(
    const float* __restrict__ T, const float* __restrict__ hnew,
    float* __restrict__ score)
{
    int warp = threadIdx.x >> 6, lane = threadIdx.x & 63;
    int l = blockIdx.x * 4 + warp;
    const float4* Tr = (const float4*)(T + (size_t)l * HQ);
    const float4* hv = (const float4*)hnew;
    float acc = 0.0f;
    #pragma unroll
    for (int i = 0; i < 4; ++i) {
        int idx = lane + i * 64;
        float4 w = Tr[idx], x = hv[idx];
        acc += w.x * x.x + w.y * x.y + w.z * x.z + w.w * x.w;
    }
    acc = wred(acc);
    if (lane == 0) score[VQ + l] = acc;
}

// ---------------- k_softmax_red ----------------
// max + sum(exp) over 34048 scores -> stats[0]=max, stats[1]=sum
__global__ __launch_bounds__(1024) void k_softmax_red(
    const float* __restrict__ score, float* __restrict__ stats)
{
    __shared__ float sred[16];
    const int N = VQ + LQ;
    int tid = threadIdx.x;
    int wid = tid >> 6, lane = tid & 63;
    float m = -3.4e38f;
    for (int i = tid; i < N; i += 1024) m = fmaxf(m, score[i]);
    m = wred_max(m);
    if (lane == 0) sred[wid] = m;
    __syncthreads();
    if (tid == 0) {
        float mm = sred[0];
        for (int i = 1; i < 16; ++i) mm = fmaxf(mm, sred[i]);
        sred[0] = mm;
    }
    __syncthreads();
    m = sred[0];
    __syncthreads();
    float s = 0.0f;
    for (int i = tid; i < N; i += 1024) s += expf(score[i] - m);
    s = wred(s);
    if (lane == 0) sred[wid] = s;
    __syncthreads();
    if (tid == 0) {
        float ss = 0.0f;
        for (int i = 0; i < 16; ++i) ss += sred[i];
        stats[0] = m;
        stats[1] = ss;
    }
}

// ---------------- k_probs_g ----------------
// d_out[i<V] = prob_g[i], d_out[V<=i<MV] = 0
__global__ __launch_bounds__(256) void k_probs_g(
    const float* __restrict__ score, const float* __restrict__ stats,
    float* __restrict__ out)
{
    int i = blockIdx.x * 256 + threadIdx.x;
    float m = stats[0], s = stats[1];
    out[i] = (i < VQ) ? expf(score[i] - m) / s : 0.0f;
}

// ---------------- k_probs_c ----------------
__global__ __launch_bounds__(256) void k_probs_c(
    const float* __restrict__ score, const float* __restrict__ stats,
    float* __restrict__ out_pc)
{
    int l = blockIdx.x * 256 + threadIdx.x;
    float m = stats[0], s = stats[1];
    out_pc[l] = expf(score[VQ + l] - m) / s;
}

// ---------------- k_scatter ----------------
__global__ __launch_bounds__(256) void k_scatter(
    const int* __restrict__ input_seq, const float* __restrict__ pc,
    float* __restrict__ out1)
{
    int l = blockIdx.x * 256 + threadIdx.x;
    atomicAdd(&out1[input_seq[l]], pc[l]);
}

// ---------------- k_log ----------------
__global__ __launch_bounds__(256) void k_log(float* __restrict__ out1)
{
    int i = blockIdx.x * 256 + threadIdx.x;
    float v = out1[i];
    if (i == 2) v = 1e-9f;
    else if (v == 0.0f) v = 1e-9f;
    out1[i] = logf(v);
}

// ---------------- host launch ----------------
extern "C" void kernel_launch(void* const* d_in, const int* in_sizes, int n_in,
                              void* d_out, int out_size, void* d_ws, size_t ws_size,
                              hipStream_t stream) {
    const int*   inp       = (const int*)  d_in[0];
    const float* hidden    = (const float*)d_in[1];
    const float* enc       = (const float*)d_in[2];
    const int*   input_seq = (const int*)  d_in[3];
    const int*   pre_prob  = (const int*)  d_in[4];
    const float* emb       = (const float*)d_in[5];
    const float* attn_W    = (const float*)d_in[6];
    const float* attn_b    = (const float*)d_in[7];
    const float* comb_W    = (const float*)d_in[8];
    const float* comb_b    = (const float*)d_in[9];
    const float* W_ih      = (const float*)d_in[10];
    const float* W_hh      = (const float*)d_in[11];
    const float* b_ih      = (const float*)d_in[12];
    const float* b_hh      = (const float*)d_in[13];
    const float* Wo_W      = (const float*)d_in[14];
    const float* Wo_b      = (const float*)d_in[15];
    const float* Wc_W      = (const float*)d_in[16];
    const float* Wc_b      = (const float*)d_in[17];

    float* out = (float*)d_out;
    float* wsf = (float*)d_ws;
    float* T      = wsf;               // 2097152
    float* xcat   = T + 2097152;       // 1536
    float* ccat   = xcat + 1536;       // 1536
    float* x2     = ccat + 1536;       // 2048 (out | sel_reading)
    float* gi     = x2 + 2048;         // 3072
    float* gh     = gi + 3072;         // 3072
    float* hnew   = gh + 3072;         // 1024
    float* logits = hnew + 1024;       // 2048
    float* score  = logits + 2048;     // 34048
    float* stats  = score + 34048;     // 2

    // independent heavy GEMM first, then the serial chain
    k_prep<<<1, 256, 0, stream>>>(inp, hidden, enc, input_seq, pre_prob, emb,
                                  xcat, ccat, x2);
    k_gemm_tanh<<<dim3(HQ / BN, LQ / BM), 256, 0, stream>>>(enc, Wc_W, Wc_b, T);
    k_attn<<<LQ / 4, 256, 0, stream>>>(attn_W, attn_b, xcat, logits);
    k_softmax_L<<<1, 1024, 0, stream>>>(logits, out + AW_OFF);
    k_attn_applied<<<dim3(EQ / 256, 16), 256, 0, stream>>>(enc, out + AW_OFF, ccat);
    k_comb<<<HQ / 4, 256, 0, stream>>>(comb_W, comb_b, ccat, x2);
    k_gru_mv<<<(3 * HQ) / 4, 256, 0, stream>>>(W_ih, W_hh, b_ih, b_hh, x2, hidden,
                                               gi, gh);
    k_gates<<<HQ / 256, 256, 0, stream>>>(gi, gh, hidden, hnew, out + HNEW_OFF);
    k_score_g<<<VQ / 4, 256, 0, stream>>>(Wo_W, Wo_b, hnew, score);
    k_score_c<<<LQ / 4, 256, 0, stream>>>(T, hnew, score);
    k_softmax_red<<<1, 1024, 0, stream>>>(score, stats);
    k_probs_g<<<MVQ / 256, 256, 0, stream>>>(score, stats, out + OUT1_OFF);
    k_probs_c<<<LQ / 256, 256, 0, stream>>>(score, stats, out + PC_OFF);
    k_scatter<<<LQ / 256, 256, 0, stream>>>(input_seq, out + PC_OFF, out + OUT1_OFF);
    k_log<<<MVQ / 256, 256, 0, stream>>>(out + OUT1_OFF);
}

// Round 2
// 138.735 us; speedup vs baseline: 1.0343x; 1.0343x over previous
//
#include <hip/hip_runtime.h>
#include <math.h>

#define LQ 2048
#define EQ 1024
#define HQ 1024
#define DQ 512
#define VQ 32000
#define MVQ 32768

// d_out layout (floats): [out1: 32768][h_new: 1024][attn_w: 2048][prob_c: 2048]
#define OUT1_OFF 0
#define HNEW_OFF 32768
#define AW_OFF   33792
#define PC_OFF   35840

#define PSZ 2097152  // one K-split partial: 2048x1024 floats

// ---------------- helpers ----------------
__device__ inline float wred(float v) {
    v += __shfl_down(v, 32);
    v += __shfl_down(v, 16);
    v += __shfl_down(v, 8);
    v += __shfl_down(v, 4);
    v += __shfl_down(v, 2);
    v += __shfl_down(v, 1);
    return v;
}
__device__ inline float wred_max(float v) {
    v = fmaxf(v, __shfl_down(v, 32));
    v = fmaxf(v, __shfl_down(v, 16));
    v = fmaxf(v, __shfl_down(v, 8));
    v = fmaxf(v, __shfl_down(v, 4));
    v = fmaxf(v, __shfl_down(v, 2));
    v = fmaxf(v, __shfl_down(v, 1));
    return v;
}
__device__ inline float sigmoidf_(float x) { return 1.0f / (1.0f + expf(-x)); }

// ---------------- k_gemm_p ----------------
// Partial C = A(2048x1024) . B(1024x1024)^T over K-slice [bz*KQ, bz*KQ+KQ).
// BM=128 (blockIdx.y), BN=256 (blockIdx.x), BK=16, 256 threads, 16x8 microtile.
// Register-prefetched staging; staging writes are <=2-way bank aliased (free).
__global__ __launch_bounds__(256, 1) void k_gemm_p(
    const float* __restrict__ A, const float* __restrict__ B,
    float* __restrict__ P, int KQ)
{
    __shared__ float As[16][132];   // [k][m], stride 132 ≡ 4 mod 32
    __shared__ float Bs[16][260];   // [k][n], stride 260 ≡ 4 mod 32
    const int t  = threadIdx.x;
    const int n0 = blockIdx.x * 256;
    const int m0 = blockIdx.y * 128;
    const int kb = blockIdx.z * KQ;
    float* Pz = P + (size_t)blockIdx.z * PSZ;

    const int c4 = t & 3;    // which float4 chunk of the 16-wide K slab
    const int r0 = t >> 2;   // 0..63
    const int tx = t & 31;   // col group: cols tx*4 and 128+tx*4
    const int ty = t >> 5;   // 0..7: rows ty*4 + 32*i, i=0..3

    const float* Abase = A + (size_t)m0 * EQ + kb + c4 * 4;
    const float* Bbase = B + (size_t)n0 * EQ + kb + c4 * 4;

    float acc[16][8];
    #pragma unroll
    for (int i = 0; i < 16; ++i)
        #pragma unroll
        for (int j = 0; j < 8; ++j) acc[i][j] = 0.0f;

    float4 ra[2], rb[4];
    #pragma unroll
    for (int i = 0; i < 2; ++i)
        ra[i] = *(const float4*)(Abase + (size_t)(r0 + 64 * i) * EQ);
    #pragma unroll
    for (int i = 0; i < 4; ++i)
        rb[i] = *(const float4*)(Bbase + (size_t)(r0 + 64 * i) * EQ);

    const int NT = KQ >> 4;
    for (int tt = 0; tt < NT; ++tt) {
        // stage regs -> LDS (transposed). bank = (16*c4 + 4j + r0) % 32 -> 2-way
        #pragma unroll
        for (int i = 0; i < 2; ++i) {
            As[c4 * 4 + 0][r0 + 64 * i] = ra[i].x;
            As[c4 * 4 + 1][r0 + 64 * i] = ra[i].y;
            As[c4 * 4 + 2][r0 + 64 * i] = ra[i].z;
            As[c4 * 4 + 3][r0 + 64 * i] = ra[i].w;
        }
        #pragma unroll
        for (int i = 0; i < 4; ++i) {
            Bs[c4 * 4 + 0][r0 + 64 * i] = rb[i].x;
            Bs[c4 * 4 + 1][r0 + 64 * i] = rb[i].y;
            Bs[c4 * 4 + 2][r0 + 64 * i] = rb[i].z;
            Bs[c4 * 4 + 3][r0 + 64 * i] = rb[i].w;
        }
        __syncthreads();
        if (tt + 1 < NT) {  // prefetch next slab; latency hides under compute
            const float* An = Abase + (tt + 1) * 16;
            const float* Bn = Bbase + (tt + 1) * 16;
            #pragma unroll
            for (int i = 0; i < 2; ++i)
                ra[i] = *(const float4*)(An + (size_t)(r0 + 64 * i) * EQ);
            #pragma unroll
            for (int i = 0; i < 4; ++i)
                rb[i] = *(const float4*)(Bn + (size_t)(r0 + 64 * i) * EQ);
        }
        #pragma unroll
        for (int kk = 0; kk < 16; ++kk) {
            float a[16], bb[8];
            #pragma unroll
            for (int i = 0; i < 4; ++i) {
                float4 v = *(const float4*)&As[kk][ty * 4 + 32 * i];
                a[4 * i + 0] = v.x; a[4 * i + 1] = v.y;
                a[4 * i + 2] = v.z; a[4 * i + 3] = v.w;
            }
            #pragma unroll
            for (int j = 0; j < 2; ++j) {
                float4 v = *(const float4*)&Bs[kk][tx * 4 + 128 * j];
                bb[4 * j + 0] = v.x; bb[4 * j + 1] = v.y;
                bb[4 * j + 2] = v.z; bb[4 * j + 3] = v.w;
            }
            #pragma unroll
            for (int i = 0; i < 16; ++i)
                #pragma unroll
                for (int j = 0; j < 8; ++j)
                    acc[i][j] = fmaf(a[i], bb[j], acc[i][j]);
        }
        __syncthreads();
    }
    #pragma unroll
    for (int i = 0; i < 4; ++i)
        #pragma unroll
        for (int r = 0; r < 4; ++r) {
            int row = m0 + ty * 4 + 32 * i + r;
            float4 o0 = make_float4(acc[i * 4 + r][0], acc[i * 4 + r][1],
                                    acc[i * 4 + r][2], acc[i * 4 + r][3]);
            float4 o1 = make_float4(acc[i * 4 + r][4], acc[i * 4 + r][5],
                                    acc[i * 4 + r][6], acc[i * 4 + r][7]);
            *(float4*)(Pz + (size_t)row * HQ + n0 + tx * 4) = o0;
            *(float4*)(Pz + (size_t)row * HQ + n0 + 128 + tx * 4) = o1;
        }
}

// ---------------- k_prep ----------------
// sel_reading with exact int32 truncation semantics -> x2[1024:2048)
__global__ __launch_bounds__(256) void k_prep(
    const int* __restrict__ inp, const float* __restrict__ enc,
    const int* __restrict__ input_seq, const int* __restrict__ pre_prob,
    float* __restrict__ x2)
{
    __shared__ int s_cnt;
    __shared__ int s_list[LQ];
    int tid = threadIdx.x;
    if (tid == 0) s_cnt = 0;
    __syncthreads();
    int tok = inp[0];
    for (int l = tid; l < LQ; l += 256) {
        if (input_seq[l] == tok && pre_prob[l] != 0) {
            int p = atomicAdd(&s_cnt, 1);
            s_list[p] = l;
        }
    }
    __syncthreads();
    int nm = s_cnt;
    for (int e = tid; e < EQ; e += 256) {
        int acc = 0;
        for (int j = 0; j < nm; ++j)
            acc += (int)enc[(size_t)s_list[j] * EQ + e];
        x2[HQ + e] = (float)acc;
    }
}

// ---------------- k_attn ----------------
// logits[r] = attn_W[r,:] . [emb_row | hidden] + attn_b[r]. Also zeroes aa.
__global__ __launch_bounds__(256) void k_attn(
    const float* __restrict__ W, const float* __restrict__ b,
    const int* __restrict__ inp, const float* __restrict__ emb,
    const float* __restrict__ hidden, float* __restrict__ logits,
    float* __restrict__ aa)
{
    int t = threadIdx.x;
    if (blockIdx.x < 4) aa[blockIdx.x * 256 + t] = 0.0f;
    int warp = t >> 6, lane = t & 63;
    int r = blockIdx.x * 4 + warp;
    int tok = inp[0];
    int ei = (tok >= VQ) ? 2 : tok;
    const float4* Wr = (const float4*)(W + (size_t)r * 1536);
    const float4* e4 = (const float4*)(emb + (size_t)ei * DQ);
    const float4* h4 = (const float4*)hidden;
    float acc = 0.0f;
    #pragma unroll
    for (int i = 0; i < 6; ++i) {
        int idx = lane + i * 64;
        float4 x = (idx < 128) ? e4[idx] : h4[idx - 128];
        float4 w = Wr[idx];
        acc += w.x * x.x + w.y * x.y + w.z * x.z + w.w * x.w;
    }
    acc = wred(acc);
    if (lane == 0) logits[r] = acc + b[r];
}

// ---------------- k_attn_sm_apply ----------------
// Fused: per-block softmax stats (deterministic, identical across blocks),
// write aw output (bx==0 blocks), accumulate aa[e] += sum_l w[l]*enc[l][e].
__global__ __launch_bounds__(256) void k_attn_sm_apply(
    const float* __restrict__ logits, const float* __restrict__ enc,
    float* __restrict__ aa, float* __restrict__ aw_out)
{
    __shared__ float sred[4];
    __shared__ float s_w[128];
    int tid = threadIdx.x, wid = tid >> 6, lane = tid & 63;
    float m = -3.4e38f;
    for (int i = tid; i < LQ; i += 256) m = fmaxf(m, logits[i]);
    m = wred_max(m);
    if (lane == 0) sred[wid] = m;
    __syncthreads();
    if (tid == 0)
        sred[0] = fmaxf(fmaxf(sred[0], sred[1]), fmaxf(sred[2], sred[3]));
    __syncthreads();
    m = sred[0];
    __syncthreads();
    float s = 0.0f;
    for (int i = tid; i < LQ; i += 256) s += expf(logits[i] - m);
    s = wred(s);
    if (lane == 0) sred[wid] = s;
    __syncthreads();
    if (tid == 0) sred[0] = sred[0] + sred[1] + sred[2] + sred[3];
    __syncthreads();
    s = sred[0];
    int l0 = blockIdx.y * 128;
    if (tid < 128) {
        float w = expf(logits[l0 + tid] - m) / s;
        s_w[tid] = w;
        if (blockIdx.x == 0) aw_out[l0 + tid] = w;
    }
    __syncthreads();
    int e = blockIdx.x * 256 + tid;
    float acc = 0.0f;
    for (int l = 0; l < 128; ++l)
        acc = fmaf(s_w[l], enc[(size_t)(l0 + l) * EQ + e], acc);
    atomicAdd(&aa[e], acc);
}

// ---------------- k_comb ----------------
// x2[r] = relu(comb_W[r,:] . [emb_row | aa] + comb_b[r])
__global__ __launch_bounds__(256) void k_comb(
    const float* __restrict__ W, const float* __restrict__ b,
    const int* __restrict__ inp, const float* __restrict__ emb,
    const float* __restrict__ aa, float* __restrict__ x2)
{
    int warp = threadIdx.x >> 6, lane = threadIdx.x & 63;
    int r = blockIdx.x * 4 + warp;
    int tok = inp[0];
    int ei = (tok >= VQ) ? 2 : tok;
    const float4* Wr = (const float4*)(W + (size_t)r * 1536);
    const float4* e4 = (const float4*)(emb + (size_t)ei * DQ);
    const float4* a4 = (const float4*)aa;
    float acc = 0.0f;
    #pragma unroll
    for (int i = 0; i < 6; ++i) {
        int idx = lane + i * 64;
        float4 x = (idx < 128) ? e4[idx] : a4[idx - 128];
        float4 w = Wr[idx];
        acc += w.x * x.x + w.y * x.y + w.z * x.z + w.w * x.w;
    }
    acc = wred(acc);
    if (lane == 0) x2[r] = fmaxf(acc + b[r], 0.0f);
}

// ---------------- k_gru_mv ----------------
__global__ __launch_bounds__(256) void k_gru_mv(
    const float* __restrict__ W_ih, const float* __restrict__ W_hh,
    const float* __restrict__ b_ih, const float* __restrict__ b_hh,
    const float* __restrict__ x2, const float* __restrict__ h,
    float* __restrict__ gi, float* __restrict__ gh)
{
    int warp = threadIdx.x >> 6, lane = threadIdx.x & 63;
    int r = blockIdx.x * 4 + warp;
    const float4* Wi = (const float4*)(W_ih + (size_t)r * 2048);
    const float4* Wh = (const float4*)(W_hh + (size_t)r * 1024);
    const float4* xv = (const float4*)x2;
    const float4* hv = (const float4*)h;
    float a1 = 0.0f, a2 = 0.0f;
    #pragma unroll
    for (int i = 0; i < 8; ++i) {
        int idx = lane + i * 64;
        float4 w = Wi[idx], x = xv[idx];
        a1 += w.x * x.x + w.y * x.y + w.z * x.z + w.w * x.w;
    }
    #pragma unroll
    for (int i = 0; i < 4; ++i) {
        int idx = lane + i * 64;
        float4 w = Wh[idx], x = hv[idx];
        a2 += w.x * x.x + w.y * x.y + w.z * x.z + w.w * x.w;
    }
    a1 = wred(a1);
    a2 = wred(a2);
    if (lane == 0) {
        gi[r] = a1 + b_ih[r];
        gh[r] = a2 + b_hh[r];
    }
}

// ---------------- k_gates ----------------
__global__ __launch_bounds__(256) void k_gates(
    const float* __restrict__ gi, const float* __restrict__ gh,
    const float* __restrict__ h, float* __restrict__ hnew,
    float* __restrict__ out_h)
{
    int i = blockIdx.x * 256 + threadIdx.x;
    float r = sigmoidf_(gi[i] + gh[i]);
    float z = sigmoidf_(gi[HQ + i] + gh[HQ + i]);
    float n = tanhf(gi[2 * HQ + i] + r * gh[2 * HQ + i]);
    float hn = (1.0f - z) * n + z * h[i];
    hnew[i] = hn;
    out_h[i] = hn;
}

// ---------------- k_scores ----------------
// r < VQ:  score[r] = Wo_W[r,:] . hnew + Wo_b[r]
// r >= VQ: l=r-VQ: score[VQ+l] = sum_h tanh(sum_z P_z[l][h] + Wc_b[h]) * hnew[h]
__global__ __launch_bounds__(256) void k_scores(
    const float* __restrict__ Wo_W, const float* __restrict__ Wo_b,
    const float* __restrict__ P, int ks,
    const float* __restrict__ Wc_b, const float* __restrict__ hnew,
    float* __restrict__ score)
{
    int warp = threadIdx.x >> 6, lane = threadIdx.x & 63;
    int r = blockIdx.x * 4 + warp;
    const float4* hv = (const float4*)hnew;
    float acc = 0.0f;
    if (r < VQ) {
        const float4* Wr = (const float4*)(Wo_W + (size_t)r * HQ);
        #pragma unroll
        for (int i = 0; i < 4; ++i) {
            int idx = lane + i * 64;
            float4 w = Wr[idx], x = hv[idx];
            acc += w.x * x.x + w.y * x.y + w.z * x.z + w.w * x.w;
        }
        acc = wred(acc);
        if (lane == 0) score[r] = acc + Wo_b[r];
    } else {
        int l = r - VQ;
        #pragma unroll
        for (int i = 0; i < 4; ++i) {
            int idx = lane + i * 64;
            float4 sv = *(const float4*)(P + (size_t)l * HQ + idx * 4);
            for (int z = 1; z < ks; ++z) {
                float4 p = *(const float4*)(P + (size_t)z * PSZ +
                                            (size_t)l * HQ + idx * 4);
                sv.x += p.x; sv.y += p.y; sv.z += p.z; sv.w += p.w;
            }
            float4 bb = *(const float4*)(Wc_b + idx * 4);
            float4 x = hv[idx];
            acc += tanhf(sv.x + bb.x) * x.x + tanhf(sv.y + bb.y) * x.y +
                   tanhf(sv.z + bb.z) * x.z + tanhf(sv.w + bb.w) * x.w;
        }
        acc = wred(acc);
        if (lane == 0) score[VQ + l] = acc;
    }
}

// ---------------- k_softmax_red ----------------
__global__ __launch_bounds__(1024) void k_softmax_red(
    const float* __restrict__ score, float* __restrict__ stats)
{
    __shared__ float sred[16];
    const int N = VQ + LQ;
    int tid = threadIdx.x;
    int wid = tid >> 6, lane = tid & 63;
    float m = -3.4e38f;
    for (int i = tid; i < N; i += 1024) m = fmaxf(m, score[i]);
    m = wred_max(m);
    if (lane == 0) sred[wid] = m;
    __syncthreads();
    if (tid == 0) {
        float mm = sred[0];
        for (int i = 1; i < 16; ++i) mm = fmaxf(mm, sred[i]);
        sred[0] = mm;
    }
    __syncthreads();
    m = sred[0];
    __syncthreads();
    float s = 0.0f;
    for (int i = tid; i < N; i += 1024) s += expf(score[i] - m);
    s = wred(s);
    if (lane == 0) sred[wid] = s;
    __syncthreads();
    if (tid == 0) {
        float ss = 0.0f;
        for (int i = 0; i < 16; ++i) ss += sred[i];
        stats[0] = m;
        stats[1] = ss;
    }
}

// ---------------- k_probs ----------------
// i < MVQ: out1[i] = prob_g or 0.  i >= MVQ: pc[i-MVQ].
__global__ __launch_bounds__(256) void k_probs(
    const float* __restrict__ score, const float* __restrict__ stats,
    float* __restrict__ out1, float* __restrict__ out_pc)
{
    int i = blockIdx.x * 256 + threadIdx.x;
    float m = stats[0], s = stats[1];
    if (i < MVQ) {
        out1[i] = (i < VQ) ? expf(score[i] - m) / s : 0.0f;
    } else {
        int l = i - MVQ;
        out_pc[l] = expf(score[VQ + l] - m) / s;
    }
}

// ---------------- k_scatter ----------------
__global__ __launch_bounds__(256) void k_scatter(
    const int* __restrict__ input_seq, const float* __restrict__ pc,
    float* __restrict__ out1)
{
    int l = blockIdx.x * 256 + threadIdx.x;
    atomicAdd(&out1[input_seq[l]], pc[l]);
}

// ---------------- k_log ----------------
__global__ __launch_bounds__(256) void k_log(float* __restrict__ out1)
{
    int i = blockIdx.x * 256 + threadIdx.x;
    float v = out1[i];
    if (i == 2 || v == 0.0f) v = 1e-9f;
    out1[i] = logf(v);
}

// ---------------- host launch ----------------
extern "C" void kernel_launch(void* const* d_in, const int* in_sizes, int n_in,
                              void* d_out, int out_size, void* d_ws, size_t ws_size,
                              hipStream_t stream) {
    const int*   inp       = (const int*)  d_in[0];
    const float* hidden    = (const float*)d_in[1];
    const float* enc       = (const float*)d_in[2];
    const int*   input_seq = (const int*)  d_in[3];
    const int*   pre_prob  = (const int*)  d_in[4];
    const float* emb       = (const float*)d_in[5];
    const float* attn_W    = (const float*)d_in[6];
    const float* attn_b    = (const float*)d_in[7];
    const float* comb_W    = (const float*)d_in[8];
    const float* comb_b    = (const float*)d_in[9];
    const float* W_ih      = (const float*)d_in[10];
    const float* W_hh      = (const float*)d_in[11];
    const float* b_ih      = (const float*)d_in[12];
    const float* b_hh      = (const float*)d_in[13];
    const float* Wo_W      = (const float*)d_in[14];
    const float* Wo_b      = (const float*)d_in[15];
    const float* Wc_W      = (const float*)d_in[16];
    const float* Wc_b      = (const float*)d_in[17];

    float* out = (float*)d_out;
    float* wsf = (float*)d_ws;

    // K-split degree: 4 if workspace allows (grid = 256 blocks), else degrade.
    const size_t small_f = 46400;
    int ks = 4;
    if (ws_size < ((size_t)4 * PSZ + small_f) * sizeof(float)) ks = 2;
    if (ws_size < ((size_t)2 * PSZ + small_f) * sizeof(float)) ks = 1;
    int KQ = EQ / ks;

    float* P      = wsf;
    float* smallb = wsf + (size_t)ks * PSZ;
    float* x2     = smallb;            // 2048 (comb out | sel_reading)
    float* gi     = x2 + 2048;         // 3072
    float* gh     = gi + 3072;         // 3072
    float* hnew   = gh + 3072;         // 1024
    float* logits = hnew + 1024;       // 2048
    float* aa     = logits + 2048;     // 1024 (attn_applied accumulator)
    float* score  = aa + 1024;         // 34048
    float* stats  = score + 34048;     // 2

    k_gemm_p<<<dim3(HQ / 256, LQ / 128, ks), 256, 0, stream>>>(enc, Wc_W, P, KQ);
    k_prep<<<1, 256, 0, stream>>>(inp, enc, input_seq, pre_prob, x2);
    k_attn<<<LQ / 4, 256, 0, stream>>>(attn_W, attn_b, inp, emb, hidden,
                                       logits, aa);
    k_attn_sm_apply<<<dim3(EQ / 256, 16), 256, 0, stream>>>(logits, enc, aa,
                                                            out + AW_OFF);
    k_comb<<<HQ / 4, 256, 0, stream>>>(comb_W, comb_b, inp, emb, aa, x2);
    k_gru_mv<<<(3 * HQ) / 4, 256, 0, stream>>>(W_ih, W_hh, b_ih, b_hh, x2,
                                               hidden, gi, gh);
    k_gates<<<HQ / 256, 256, 0, stream>>>(gi, gh, hidden, hnew, out + HNEW_OFF);
    k_scores<<<(VQ + LQ) / 4, 256, 0, stream>>>(Wo_W, Wo_b, P, ks, Wc_b, hnew,
                                                score);
    k_softmax_red<<<1, 1024, 0, stream>>>(score, stats);
    k_probs<<<(MVQ + LQ) / 256, 256, 0, stream>>>(score, stats, out + OUT1_OFF,
                                                  out + PC_OFF);
    k_scatter<<<LQ / 256, 256, 0, stream>>>(input_seq, out + PC_OFF,
                                            out + OUT1_OFF);
    k_log<<<MVQ / 256, 256, 0, stream>>>(out + OUT1_OFF);
}